// Round 8
// baseline (608.686 us; speedup 1.0000x reference)
//
#include <hip/hip_runtime.h>
#include <hip/hip_bf16.h>
#include <hip/hip_cooperative_groups.h>

namespace cg = cooperative_groups;

#define D_MODEL 1024
#define D_STATE 16
#define L_SEQ 2048
#define B_SZ 4
#define M_ROWS (B_SZ * L_SEQ)   // 8192
#define N_CHUNK 32
#define C_LEN 64

typedef __attribute__((ext_vector_type(8))) short short8;
typedef __attribute__((ext_vector_type(4))) float f32x4;

#define SBAR()  asm volatile("s_barrier" ::: "memory")
#define GATE(N) asm volatile("s_waitcnt vmcnt(" #N ") lgkmcnt(0)\n\ts_barrier" ::: "memory")

typedef const unsigned short __attribute__((address_space(1))) gas_us;
typedef unsigned short __attribute__((address_space(3))) las_us;
static __device__ __forceinline__ void gload16(const unsigned short* g, unsigned short* l) {
    __builtin_amdgcn_global_load_lds((gas_us*)g, (las_us*)l, 16, 0, 0);
}

static __device__ __forceinline__ unsigned short f2bf(float f) {
    unsigned int u = __float_as_uint(f);
    unsigned int r = (u + 0x7FFFu + ((u >> 16) & 1u)) >> 16;   // RNE
    return (unsigned short)r;
}
static __device__ __forceinline__ float bf2f(unsigned short u) {
    return __uint_as_float(((unsigned int)u) << 16);
}

// ---- gemm1 (8-phase m201-style) macros: operate on stage-local names ----
#define STG(B_, MAT_, KH_, GPTR_, KOFF_) do { \
    unsigned short* d_ = lbase + (B_)*32768 + (MAT_)*16384 + (KH_)*8192 + wave*1024; \
    gload16((GPTR_) + (KOFF_), d_); \
    gload16((GPTR_) + 16*K + (KOFF_), d_ + 512); } while(0)

#define PH(B_, KS_, MG_, READB_, STAGE_, TAIL_) { \
    if (READB_) { \
        _Pragma("unroll") for (int j_ = 0; j_ < 4; ++j_) \
            bv[j_] = *(const short8*)(ldsB + (B_)*65536 + (KS_)*16384 + (wn*4 + j_)*1024); \
    } \
    short8 av[4]; \
    _Pragma("unroll") for (int i_ = 0; i_ < 4; ++i_) \
        av[i_] = *(const short8*)(ldsA + (B_)*65536 + (KS_)*16384 + (wm*8 + (MG_)*4 + i_)*1024); \
    STAGE_; \
    SBAR(); \
    asm volatile("s_waitcnt lgkmcnt(0)" ::: "memory"); \
    __builtin_amdgcn_s_setprio(1); \
    _Pragma("unroll") for (int i_ = 0; i_ < 4; ++i_) { \
        _Pragma("unroll") for (int j_ = 0; j_ < 4; ++j_) \
            acc[(MG_)*4 + i_][j_] = __builtin_amdgcn_mfma_f32_16x16x32_bf16( \
                av[i_], bv[j_], acc[(MG_)*4 + i_][j_], 0, 0, 0); } \
    __builtin_amdgcn_s_setprio(0); \
    TAIL_; \
}

// ---- gemm2 (4-slot lead-3) macros ----
#define MFMA16(ACC, AV, BV) { \
    _Pragma("unroll") for (int i_ = 0; i_ < 4; ++i_) { \
        _Pragma("unroll") for (int jf_ = 0; jf_ < 4; ++jf_) \
            ACC[i_][jf_] = __builtin_amdgcn_mfma_f32_16x16x32_bf16( \
                AV[i_], BV[jf_], ACC[i_][jf_], 0, 0, 0); } }

#define STAGE2(J) { size_t ko_ = (size_t)(J) * 32; int so_ = ((J) & 3) * 12288; \
    gload16(pA0 + ko_, dA + so_); gload16(pB0 + ko_, dB0 + so_); gload16(pB1 + ko_, dB1 + so_); }

#define G2_TILE(J, DOSTAGE, TRAIL) { \
    const int slot_ = (J) & 3; \
    const char* rA_ = ldsA_rd + slot_ * 24576; \
    const char* rB_ = ldsB_rd + slot_ * 24576; \
    short8 av[4], bv[4]; \
    _Pragma("unroll") for (int i_ = 0; i_ < 4; ++i_) av[i_] = *(const short8*)(rA_ + i_ * 1024); \
    _Pragma("unroll") for (int j_ = 0; j_ < 4; ++j_) bv[j_] = *(const short8*)(rB_ + j_ * 1024); \
    if (DOSTAGE) { STAGE2((J) + 3); } \
    SBAR(); \
    __builtin_amdgcn_s_setprio(1); \
    MFMA16(acc, av, bv); \
    __builtin_amdgcn_s_setprio(0); \
    TRAIL; \
}

// ============================================================================
// Mega-kernel: prep -> gemm1 -> scan -> gemm2 in ONE cooperative launch.
// 256 blocks x 512 threads, 1 block/CU (128KB LDS union forces it; co-residency
// required for grid.sync). __threadfence() (device scope, wbl2) before each
// grid.sync makes stage writes visible die-wide via L3; no reader holds stale
// lines (every buffer is write-then-read-once within the kernel).
// ============================================================================
__global__ __launch_bounds__(512, 1) void mega_kernel(
    const float* __restrict__ x, const float* __restrict__ A_log,
    const float* __restrict__ Bp, const float* __restrict__ Cp,
    const float* __restrict__ log_dt, const float* __restrict__ in_w,
    const float* __restrict__ in_b, const float* __restrict__ out_w,
    const float* __restrict__ out_b, const float* __restrict__ ln_g,
    const float* __restrict__ ln_b, float* __restrict__ out,
    unsigned short* __restrict__ xn, unsigned short* __restrict__ w1,
    unsigned short* __restrict__ u, unsigned short* __restrict__ zs,
    unsigned short* __restrict__ yz, unsigned short* __restrict__ w2)
{
    __shared__ __align__(16) unsigned char smem[131072];   // 128 KB union
    cg::grid_group grid = cg::this_grid();

    int bid = blockIdx.x;
    int t = threadIdx.x;
    int lane = t & 63;
    int wave = t >> 6;

    // ===================== stage 0: prep (LN + weight conv) =================
    {
        float* sred = (float*)smem;          // [2][8]: 4 sums + 4 sumsqs per half
        int sb = t >> 8;                     // 0..1: which of 2 concurrent rows
        int tt = t & 255;
        #pragma unroll 1
        for (int i = 0; i < 16; ++i) {
            int row = bid * 32 + i * 2 + sb;
            const float4* xr = (const float4*)(x + (size_t)row * D_MODEL);
            float4 v = xr[tt];
            float s  = v.x + v.y + v.z + v.w;
            float ss = v.x * v.x + v.y * v.y + v.z * v.z + v.w * v.w;
            #pragma unroll
            for (int o = 32; o > 0; o >>= 1) {
                s  += __shfl_down(s,  o);
                ss += __shfl_down(ss, o);
            }
            int wid = tt >> 6;               // 0..3 within the 256-thread half
            if ((tt & 63) == 0) { sred[sb * 8 + wid] = s; sred[sb * 8 + 4 + wid] = ss; }
            __syncthreads();
            float S  = sred[sb * 8 + 0] + sred[sb * 8 + 1] + sred[sb * 8 + 2] + sred[sb * 8 + 3];
            float SS = sred[sb * 8 + 4] + sred[sb * 8 + 5] + sred[sb * 8 + 6] + sred[sb * 8 + 7];
            float mu  = S * (1.0f / D_MODEL);
            float var = SS * (1.0f / D_MODEL) - mu * mu;
            float inv = rsqrtf(var + 1e-5f);
            float4 gv = ((const float4*)ln_g)[tt];
            float4 bv = ((const float4*)ln_b)[tt];
            ushort4 o;
            o.x = f2bf((v.x - mu) * inv * gv.x + bv.x);
            o.y = f2bf((v.y - mu) * inv * gv.y + bv.y);
            o.z = f2bf((v.z - mu) * inv * gv.z + bv.z);
            o.w = f2bf((v.w - mu) * inv * gv.w + bv.w);
            ((ushort4*)(xn + (size_t)row * D_MODEL))[tt] = o;
            __syncthreads();
        }
        // weights: 786432 float4 total = 6 per thread (uniform branch per k)
        int idx = bid * 512 + t;             // 0..131071
        #pragma unroll
        for (int k2 = 0; k2 < 6; ++k2) {
            int j = k2 * 131072 + idx;
            if (j < 524288) {
                float4 v = ((const float4*)in_w)[j];
                ushort4 o;
                o.x = f2bf(v.x); o.y = f2bf(v.y); o.z = f2bf(v.z); o.w = f2bf(v.w);
                ((ushort4*)w1)[j] = o;
            } else {
                int j2 = j - 524288;
                float4 v = ((const float4*)out_w)[j2];
                ushort4 o;
                o.x = f2bf(v.x); o.y = f2bf(v.y); o.z = f2bf(v.z); o.w = f2bf(v.w);
                ((ushort4*)w2)[j2] = o;
            }
        }
    }
    __threadfence();
    grid.sync();
    __threadfence();

    // ===================== stage 1: gemm1 (R6 8-phase, 256x256, BK=64) ======
    {
        const int K = D_MODEL;
        int wm = wave >> 2;
        int wn = wave & 3;
        int swz = (bid & 7) * 32 + (bid >> 3);
        int m0 = (swz >> 3) * 256;
        int n0 = (swz & 7) * 256;

        int srow = lane >> 2;
        int sk = ((lane & 3) * 8) ^ ((lane & 32) >> 1);
        const unsigned short* gA = xn + (size_t)(m0 + wave * 32 + srow) * K + sk;
        const unsigned short* gB = w1 + (size_t)(n0 + wave * 32 + srow) * K + sk;

        unsigned short* lbase = (unsigned short*)smem;
        int off_base = (lane & 15) * 64 + (((lane >> 4) * 16) ^ ((lane & 8) * 4));
        const char* ldsA = (const char*)lbase + off_base;
        const char* ldsB = (const char*)lbase + 32768 + off_base;

        f32x4 acc[8][4] = {};
        short8 bv[4];

        STG(0, 0, 0, gA, 0);  STG(0, 1, 0, gB, 0);
        STG(0, 0, 1, gA, 32); STG(0, 1, 1, gB, 32);
        STG(1, 0, 0, gA, 64); STG(1, 1, 0, gB, 64);
        GATE(4);

        int ko = 0;
        #pragma unroll 1
        for (int it = 0; it < 7; ++it) {
            PH(0, 0, 0, true,  STG(1, 0, 1, gA, ko + 96),  SBAR());
            PH(0, 0, 1, false, STG(1, 1, 1, gB, ko + 96),  SBAR());
            PH(0, 1, 0, true,  STG(0, 0, 0, gA, ko + 128), SBAR());
            PH(0, 1, 1, false, STG(0, 1, 0, gB, ko + 128), GATE(4));
            PH(1, 0, 0, true,  STG(0, 0, 1, gA, ko + 160), SBAR());
            PH(1, 0, 1, false, STG(0, 1, 1, gB, ko + 160), SBAR());
            PH(1, 1, 0, true,  STG(1, 0, 0, gA, ko + 192), SBAR());
            PH(1, 1, 1, false, STG(1, 1, 0, gB, ko + 192), GATE(4));
            ko += 128;
        }
        PH(0, 0, 0, true,  STG(1, 0, 1, gA, ko + 96), SBAR());
        PH(0, 0, 1, false, STG(1, 1, 1, gB, ko + 96), SBAR());
        PH(0, 1, 0, true,  (void)0, SBAR());
        PH(0, 1, 1, false, (void)0, GATE(0));
        PH(1, 0, 0, true,  (void)0, SBAR());
        PH(1, 0, 1, false, (void)0, SBAR());
        PH(1, 1, 0, true,  (void)0, SBAR());
        PH(1, 1, 1, false, (void)0, (void)0);

        int col = lane & 15;
        int quad = lane >> 4;
        float bs[4];
        #pragma unroll
        for (int jf = 0; jf < 4; ++jf) bs[jf] = in_b[n0 + wn * 64 + jf * 16 + col];
        bool isU = (n0 < D_MODEL);
        int nbase = isU ? (n0 + wn * 64 + col) : (n0 - D_MODEL + wn * 64 + col);
        unsigned short* obase = isU ? u : zs;
        #pragma unroll
        for (int i = 0; i < 8; ++i) {
            #pragma unroll
            for (int r = 0; r < 4; ++r) {
                int m = m0 + wm * 128 + i * 16 + quad * 4 + r;
                unsigned short* orow = obase + (size_t)m * D_MODEL + nbase;
                #pragma unroll
                for (int jf = 0; jf < 4; ++jf) {
                    float v = acc[i][jf][r] + bs[jf];
                    if (!isU) v = v / (1.0f + __expf(-v));
                    orow[jf * 16] = f2bf(v);
                }
            }
        }
    }
    __threadfence();
    grid.sync();
    __threadfence();

    // ===================== stage 2: scan (LDS-staged v2) ====================
    {
        unsigned short* uslab = (unsigned short*)smem;                          // 64 KB
        float (*S)[D_STATE][17] = reinterpret_cast<float (*)[D_STATE][17]>(smem + 65536); // 34.8 KB

        int l  = (bid & 7) * 32 + (bid >> 3);
        int b  = l >> 6;
        int dg = l & 63;
        int c  = t >> 4;
        int dl = t & 15;
        int d  = dg * 16 + dl;

        {
            const unsigned short* src = u + ((size_t)b * L_SEQ + wave * 32 + (lane >> 1)) * D_MODEL
                                          + dg * 16 + (lane & 1) * 8;
            #pragma unroll
            for (int i = 0; i < 8; ++i)
                gload16(src + (size_t)i * 256 * D_MODEL, uslab + (i * 256 + wave * 32) * 16);
        }

        float dt = fminf(1.0f, fmaxf(1e-4f, __expf(log_dt[d])));
        float ab[D_STATE];
        #pragma unroll
        for (int n = 0; n < D_STATE; n++) {
            float a = __expf(-__expf(A_log[d * D_STATE + n]) * dt);
            ab[n] = fminf(1.0f - 1e-8f, fmaxf(1e-8f, a));
        }
        float cb[D_STATE];
        #pragma unroll
        for (int n = 0; n < D_STATE; n++)
            cb[n] = Cp[d * D_STATE + n] * Bp[d * D_STATE + n] * dt;

        asm volatile("s_waitcnt vmcnt(0)" ::: "memory");
        __syncthreads();

        const unsigned short* rcol = uslab + (c * 64) * 16 + dl;
        float P[D_STATE];
        #pragma unroll
        for (int n = 0; n < D_STATE; n++) P[n] = 0.0f;
        #pragma unroll 4
        for (int tt = 0; tt < C_LEN; tt++) {
            float uv = bf2f(rcol[tt * 16]);
            #pragma unroll
            for (int n = 0; n < D_STATE; n++) P[n] = fmaf(ab[n], P[n], uv);
        }

        #pragma unroll
        for (int n = 0; n < D_STATE; n++) S[c][n][dl] = P[n];

        float m[D_STATE];
        #pragma unroll
        for (int n = 0; n < D_STATE; n++) {
            float a2 = ab[n];
            #pragma unroll
            for (int q = 0; q < 6; q++) a2 = a2 * a2;   // a^64
            m[n] = a2;
        }
        __syncthreads();

        #pragma unroll
        for (int k = 1; k < N_CHUNK; k <<= 1) {
            float tmp[D_STATE];
            #pragma unroll
            for (int n = 0; n < D_STATE; n++) tmp[n] = (c >= k) ? S[c - k][n][dl] : 0.0f;
            __syncthreads();
            #pragma unroll
            for (int n = 0; n < D_STATE; n++) {
                P[n] = fmaf(m[n], tmp[n], P[n]);
                S[c][n][dl] = P[n];
            }
            #pragma unroll
            for (int n = 0; n < D_STATE; n++) m[n] = m[n] * m[n];
            __syncthreads();
        }

        float s2[D_STATE];
        #pragma unroll
        for (int n = 0; n < D_STATE; n++) s2[n] = (c == 0) ? 0.0f : S[c - 1][n][dl];

        unsigned short* wcol = uslab + (c * 64) * 16 + dl;
        #pragma unroll 4
        for (int tt = 0; tt < C_LEN; tt++) {
            float uv = bf2f(wcol[tt * 16]);
            #pragma unroll
            for (int n = 0; n < D_STATE; n++) s2[n] = fmaf(ab[n], s2[n], uv);
            float y = 0.0f;
            #pragma unroll
            for (int n = 0; n < D_STATE; n++) y = fmaf(cb[n], s2[n], y);
            wcol[tt * 16] = f2bf(y);
        }
        __syncthreads();

        {
            size_t gbase = (size_t)b * L_SEQ * D_MODEL + (size_t)dg * 16;
            #pragma unroll
            for (int i = 0; i < 8; ++i) {
                int idx = i * 512 + t;
                int row = idx >> 1, half = idx & 1;
                size_t go = gbase + (size_t)row * D_MODEL + half * 8;
                short8 zv = *(const short8*)(zs + go);
                short8 yv = *(const short8*)(uslab + idx * 8);
                short8 o;
                #pragma unroll
                for (int e = 0; e < 8; ++e)
                    o[e] = (short)f2bf(bf2f((unsigned short)yv[e]) * bf2f((unsigned short)zv[e]));
                *(short8*)(yz + go) = o;
            }
        }
    }
    __threadfence();
    grid.sync();
    __threadfence();

    // ===================== stage 3: gemm2 (R2 4-slot lead-3) ================
    {
        const int K = D_MODEL;
        int wm = wave >> 2;
        int wn = wave & 3;
        int swz = (bid & 7) * 32 + (bid >> 3);
        int m0 = (swz >> 2) * 128;
        int n0 = (swz & 3) * 256;

        int srow = lane >> 2;
        int sk = ((lane & 3) * 8) ^ ((lane & 32) >> 1);
        const unsigned short* pA0 = yz + (size_t)(m0 + wave * 16 + srow) * K + sk;
        const unsigned short* pB0 = w2 + (size_t)(n0 + wave * 16 + srow) * K + sk;
        const unsigned short* pB1 = pB0 + (size_t)128 * K;

        unsigned short* lds2 = (unsigned short*)smem;
        unsigned short* dA  = lds2 + wave * 512;
        unsigned short* dB0 = lds2 + 4096 + wave * 512;
        unsigned short* dB1 = lds2 + 8192 + wave * 512;

        int off_base = (lane & 15) * 64 + (((lane >> 4) * 16) ^ ((lane & 8) * 4));
        const char* ldsA_rd = (const char*)lds2 + wm * 4096 + off_base;
        const char* ldsB_rd = (const char*)lds2 + 8192 + wn * 4096 + off_base;

        f32x4 acc[4][4] = {};

        STAGE2(0); STAGE2(1); STAGE2(2);
        GATE(6);

        #pragma unroll 1
        for (int j = 0; j < 29; ++j) { G2_TILE(j, true, GATE(6)); }
        G2_TILE(29, false, GATE(3));
        G2_TILE(30, false, GATE(0));
        G2_TILE(31, false, (void)0);

        int col = lane & 15;
        int quad = lane >> 4;
        float bs[4];
        #pragma unroll
        for (int jf = 0; jf < 4; ++jf) bs[jf] = out_b[n0 + wn * 64 + jf * 16 + col];
        #pragma unroll
        for (int i = 0; i < 4; ++i) {
            #pragma unroll
            for (int r = 0; r < 4; ++r) {
                int m = m0 + wm * 64 + i * 16 + quad * 4 + r;
                const float* rrow = x + (size_t)m * D_MODEL + n0 + wn * 64 + col;
                float* orow = out + (size_t)m * D_MODEL + n0 + wn * 64 + col;
                #pragma unroll
                for (int jf = 0; jf < 4; ++jf) {
                    float y = acc[i][jf][r] + bs[jf] + rrow[jf * 16];
                    y = fminf(10.0f, fmaxf(-10.0f, y));
                    orow[jf * 16] = y;
                }
            }
        }
    }
}

extern "C" void kernel_launch(void* const* d_in, const int* in_sizes, int n_in,
                              void* d_out, int out_size, void* d_ws, size_t ws_size,
                              hipStream_t stream) {
    const float* x       = (const float*)d_in[0];
    const float* A_log   = (const float*)d_in[1];
    const float* B_param = (const float*)d_in[2];
    const float* C_param = (const float*)d_in[3];
    const float* log_dt  = (const float*)d_in[4];
    const float* in_w    = (const float*)d_in[5];
    const float* in_b    = (const float*)d_in[6];
    const float* out_w   = (const float*)d_in[7];
    const float* out_b   = (const float*)d_in[8];
    const float* ln_g    = (const float*)d_in[9];
    const float* ln_b    = (const float*)d_in[10];
    float* out = (float*)d_out;

    char* ws = (char*)d_ws;
    size_t off = 0;
    unsigned short* xn = (unsigned short*)(ws + off); off += (size_t)M_ROWS * D_MODEL * 2;        // 16 MB
    unsigned short* w1 = (unsigned short*)(ws + off); off += (size_t)2 * D_MODEL * D_MODEL * 2;   // 4 MB
    unsigned short* u  = (unsigned short*)(ws + off); off += (size_t)M_ROWS * D_MODEL * 2;        // 16 MB
    unsigned short* zs = (unsigned short*)(ws + off); off += (size_t)M_ROWS * D_MODEL * 2;        // 16 MB
    unsigned short* yz = (unsigned short*)(ws + off); off += (size_t)M_ROWS * D_MODEL * 2;        // 16 MB
    unsigned short* w2 = (unsigned short*)(ws + off); off += (size_t)D_MODEL * D_MODEL * 2;       // 2 MB

    void* kargs[] = {
        (void*)&x, (void*)&A_log, (void*)&B_param, (void*)&C_param, (void*)&log_dt,
        (void*)&in_w, (void*)&in_b, (void*)&out_w, (void*)&out_b, (void*)&ln_g,
        (void*)&ln_b, (void*)&out, (void*)&xn, (void*)&w1, (void*)&u, (void*)&zs,
        (void*)&yz, (void*)&w2
    };
    hipLaunchCooperativeKernel(reinterpret_cast<void*>(mega_kernel),
                               dim3(256), dim3(512), kargs, 0, stream);
}

// Round 9
// 197.575 us; speedup vs baseline: 3.0808x; 3.0808x over previous
//
#include <hip/hip_runtime.h>
#include <hip/hip_bf16.h>

#define D_MODEL 1024
#define D_STATE 16
#define L_SEQ 2048
#define B_SZ 4
#define M_ROWS (B_SZ * L_SEQ)   // 8192
#define N_CHUNK 32               // chunks per sequence
#define C_LEN 64                 // timesteps per chunk (32*64 = 2048)

typedef __attribute__((ext_vector_type(8))) short short8;
typedef __attribute__((ext_vector_type(4))) float f32x4;

#define SBAR()  asm volatile("s_barrier" ::: "memory")
#define GATE(N) asm volatile("s_waitcnt vmcnt(" #N ") lgkmcnt(0)\n\ts_barrier" ::: "memory")

typedef const unsigned short __attribute__((address_space(1))) gas_us;
typedef unsigned short __attribute__((address_space(3))) las_us;
static __device__ __forceinline__ void gload16(const unsigned short* g, unsigned short* l) {
    // global -> LDS DMA, 16B per lane, dest = wave-uniform base + lane*16
    __builtin_amdgcn_global_load_lds((gas_us*)g, (las_us*)l, 16, 0, 0);
}

static __device__ __forceinline__ unsigned short f2bf(float f) {
    unsigned int u = __float_as_uint(f);
    unsigned int r = (u + 0x7FFFu + ((u >> 16) & 1u)) >> 16;   // RNE
    return (unsigned short)r;
}
static __device__ __forceinline__ float bf2f(unsigned short u) {
    return __uint_as_float(((unsigned int)u) << 16);
}

// ---------------- fused prep: LN rows + weight bf16 conversion ----------------
__global__ __launch_bounds__(256) void prep_kernel(const float* __restrict__ x,
                                                   const float* __restrict__ g,
                                                   const float* __restrict__ b,
                                                   unsigned short* __restrict__ xn,
                                                   const float* __restrict__ in_w,
                                                   unsigned short* __restrict__ w1,
                                                   const float* __restrict__ out_w,
                                                   unsigned short* __restrict__ w2) {
    __shared__ float sbuf[8];
    int bid = blockIdx.x;
    int t = threadIdx.x;
    if (bid < M_ROWS) {
        int row = bid;
        const float4* xr = (const float4*)(x + (size_t)row * D_MODEL);
        float4 v = xr[t];
        float s  = v.x + v.y + v.z + v.w;
        float ss = v.x * v.x + v.y * v.y + v.z * v.z + v.w * v.w;
        #pragma unroll
        for (int o = 32; o > 0; o >>= 1) {
            s  += __shfl_down(s,  o);
            ss += __shfl_down(ss, o);
        }
        int wid = t >> 6;
        if ((t & 63) == 0) { sbuf[wid] = s; sbuf[4 + wid] = ss; }
        __syncthreads();
        float S  = sbuf[0] + sbuf[1] + sbuf[2] + sbuf[3];
        float SS = sbuf[4] + sbuf[5] + sbuf[6] + sbuf[7];
        float mu  = S * (1.0f / D_MODEL);
        float var = SS * (1.0f / D_MODEL) - mu * mu;
        float inv = rsqrtf(var + 1e-5f);
        float4 gv = ((const float4*)g)[t];
        float4 bv = ((const float4*)b)[t];
        ushort4 o;
        o.x = f2bf((v.x - mu) * inv * gv.x + bv.x);
        o.y = f2bf((v.y - mu) * inv * gv.y + bv.y);
        o.z = f2bf((v.z - mu) * inv * gv.z + bv.z);
        o.w = f2bf((v.w - mu) * inv * gv.w + bv.w);
        ((ushort4*)(xn + (size_t)row * D_MODEL))[t] = o;
    } else if (bid < M_ROWS + 2048) {
        int i = (bid - M_ROWS) * 256 + t;
        float4 v = ((const float4*)in_w)[i];
        ushort4 o;
        o.x = f2bf(v.x); o.y = f2bf(v.y); o.z = f2bf(v.z); o.w = f2bf(v.w);
        ((ushort4*)w1)[i] = o;
    } else {
        int i = (bid - M_ROWS - 2048) * 256 + t;
        float4 v = ((const float4*)out_w)[i];
        ushort4 o;
        o.x = f2bf(v.x); o.y = f2bf(v.y); o.z = f2bf(v.z); o.w = f2bf(v.w);
        ((ushort4*)w2)[i] = o;
    }
}

// ============================================================================
// GEMM1: m201-style 8-phase schedule (R6 exact — fastest measured: 43.2 us).
// 256x256 tile, BK=64, 2 K-tile LDS double-buffer (128KB). 8 waves (2m x 4n),
// wave tile 128x64, acc[8][4]. vmcnt(4) gates at phases 4/8 only.
// ============================================================================
#define STG(B_, MAT_, KH_, GPTR_, KOFF_) do { \
    unsigned short* d_ = lbase + (B_)*32768 + (MAT_)*16384 + (KH_)*8192 + wave*1024; \
    gload16((GPTR_) + (KOFF_), d_); \
    gload16((GPTR_) + 16*K + (KOFF_), d_ + 512); } while(0)

#define PH(B_, KS_, MG_, READB_, STAGE_, TAIL_) { \
    if (READB_) { \
        _Pragma("unroll") for (int j_ = 0; j_ < 4; ++j_) \
            bv[j_] = *(const short8*)(ldsB + (B_)*65536 + (KS_)*16384 + (wn*4 + j_)*1024); \
    } \
    short8 av[4]; \
    _Pragma("unroll") for (int i_ = 0; i_ < 4; ++i_) \
        av[i_] = *(const short8*)(ldsA + (B_)*65536 + (KS_)*16384 + (wm*8 + (MG_)*4 + i_)*1024); \
    STAGE_; \
    SBAR(); \
    asm volatile("s_waitcnt lgkmcnt(0)" ::: "memory"); \
    __builtin_amdgcn_s_setprio(1); \
    _Pragma("unroll") for (int i_ = 0; i_ < 4; ++i_) { \
        _Pragma("unroll") for (int j_ = 0; j_ < 4; ++j_) \
            acc[(MG_)*4 + i_][j_] = __builtin_amdgcn_mfma_f32_16x16x32_bf16( \
                av[i_], bv[j_], acc[(MG_)*4 + i_][j_], 0, 0, 0); } \
    __builtin_amdgcn_s_setprio(0); \
    TAIL_; \
}

__global__ __launch_bounds__(512, 1) void gemm1_kernel(const unsigned short* __restrict__ A,
                                                       const unsigned short* __restrict__ Bt,
                                                       const float* __restrict__ bias,
                                                       unsigned short* __restrict__ u_bf,
                                                       unsigned short* __restrict__ zs) {
    __shared__ __align__(16) unsigned short lds[2][32768];   // 128 KB
    const int K = D_MODEL;

    int t = threadIdx.x;
    int lane = t & 63;
    int wave = t >> 6;
    int wm = wave >> 2;          // 0..1 -> A half (128 rows)
    int wn = wave & 3;           // 0..3 -> B quarter (64 rows)

    int bid = blockIdx.x;
    int swz = (bid & 7) * 32 + (bid >> 3);
    int m0 = (swz >> 3) * 256;
    int n0 = (swz & 7) * 256;

    int srow = lane >> 2;
    int sk = ((lane & 3) * 8) ^ ((lane & 32) >> 1);
    const unsigned short* gA = A  + (size_t)(m0 + wave * 32 + srow) * K + sk;
    const unsigned short* gB = Bt + (size_t)(n0 + wave * 32 + srow) * K + sk;

    unsigned short* lbase = &lds[0][0];

    int off_base = (lane & 15) * 64 + (((lane >> 4) * 16) ^ ((lane & 8) * 4));
    const char* ldsA = (const char*)lbase + off_base;
    const char* ldsB = (const char*)lbase + 32768 + off_base;

    f32x4 acc[8][4] = {};
    short8 bv[4];

    // prologue: T0 fully (8 loads), T1.kh0 (4 loads); GATE(4) -> T0 landed
    STG(0, 0, 0, gA, 0);  STG(0, 1, 0, gB, 0);
    STG(0, 0, 1, gA, 32); STG(0, 1, 1, gB, 32);
    STG(1, 0, 0, gA, 64); STG(1, 1, 0, gB, 64);
    GATE(4);

    int ko = 0;
    #pragma unroll 1
    for (int it = 0; it < 7; ++it) {
        PH(0, 0, 0, true,  STG(1, 0, 1, gA, ko + 96),  SBAR());
        PH(0, 0, 1, false, STG(1, 1, 1, gB, ko + 96),  SBAR());
        PH(0, 1, 0, true,  STG(0, 0, 0, gA, ko + 128), SBAR());
        PH(0, 1, 1, false, STG(0, 1, 0, gB, ko + 128), GATE(4));
        PH(1, 0, 0, true,  STG(0, 0, 1, gA, ko + 160), SBAR());
        PH(1, 0, 1, false, STG(0, 1, 1, gB, ko + 160), SBAR());
        PH(1, 1, 0, true,  STG(1, 0, 0, gA, ko + 192), SBAR());
        PH(1, 1, 1, false, STG(1, 1, 0, gB, ko + 192), GATE(4));
        ko += 128;
    }
    PH(0, 0, 0, true,  STG(1, 0, 1, gA, ko + 96), SBAR());
    PH(0, 0, 1, false, STG(1, 1, 1, gB, ko + 96), SBAR());
    PH(0, 1, 0, true,  (void)0, SBAR());
    PH(0, 1, 1, false, (void)0, GATE(0));
    PH(1, 0, 0, true,  (void)0, SBAR());
    PH(1, 0, 1, false, (void)0, SBAR());
    PH(1, 1, 0, true,  (void)0, SBAR());
    PH(1, 1, 1, false, (void)0, (void)0);

    int col = lane & 15;
    int quad = lane >> 4;
    float bs[4];
    #pragma unroll
    for (int jf = 0; jf < 4; ++jf) bs[jf] = bias[n0 + wn * 64 + jf * 16 + col];
    bool isU = (n0 < D_MODEL);               // uniform per block
    int nbase = isU ? (n0 + wn * 64 + col) : (n0 - D_MODEL + wn * 64 + col);
    unsigned short* obase = isU ? u_bf : zs;
    #pragma unroll
    for (int i = 0; i < 8; ++i) {
        #pragma unroll
        for (int r = 0; r < 4; ++r) {
            int m = m0 + wm * 128 + i * 16 + quad * 4 + r;
            unsigned short* orow = obase + (size_t)m * D_MODEL + nbase;
            #pragma unroll
            for (int jf = 0; jf < 4; ++jf) {
                float v = acc[i][jf][r] + bs[jf];
                if (!isU) v = v / (1.0f + __expf(-v));
                orow[jf * 16] = f2bf(v);
            }
        }
    }
}

// ============================================================================
// GEMM2: 128x256 tile, BK=32, 4 LDS slots (24KB each), lead-3 pipeline (R2).
// ============================================================================
#define MFMA16(ACC, AV, BV) { \
    _Pragma("unroll") for (int i_ = 0; i_ < 4; ++i_) { \
        _Pragma("unroll") for (int jf_ = 0; jf_ < 4; ++jf_) \
            ACC[i_][jf_] = __builtin_amdgcn_mfma_f32_16x16x32_bf16( \
                AV[i_], BV[jf_], ACC[i_][jf_], 0, 0, 0); } }

#define STAGE2(J) { size_t ko_ = (size_t)(J) * 32; int so_ = ((J) & 3) * 12288; \
    gload16(pA0 + ko_, dA + so_); gload16(pB0 + ko_, dB0 + so_); gload16(pB1 + ko_, dB1 + so_); }

#define G2_TILE(J, DOSTAGE, TRAIL) { \
    const int slot_ = (J) & 3; \
    const char* rA_ = ldsA_rd + slot_ * 24576; \
    const char* rB_ = ldsB_rd + slot_ * 24576; \
    short8 av[4], bv[4]; \
    _Pragma("unroll") for (int i_ = 0; i_ < 4; ++i_) av[i_] = *(const short8*)(rA_ + i_ * 1024); \
    _Pragma("unroll") for (int j_ = 0; j_ < 4; ++j_) bv[j_] = *(const short8*)(rB_ + j_ * 1024); \
    if (DOSTAGE) { STAGE2((J) + 3); } \
    SBAR(); \
    __builtin_amdgcn_s_setprio(1); \
    MFMA16(acc, av, bv); \
    __builtin_amdgcn_s_setprio(0); \
    TRAIL; \
}

__global__ __launch_bounds__(512, 2) void gemm2_kernel(const unsigned short* __restrict__ A,
                                                       const unsigned short* __restrict__ Bt,
                                                       const float* __restrict__ bias,
                                                       float* __restrict__ out_f,
                                                       const float* __restrict__ resid) {
    __shared__ __align__(16) unsigned short lds[4][12288];   // 96 KB
    const int K = D_MODEL;

    int t = threadIdx.x;
    int lane = t & 63;
    int wave = t >> 6;
    int wm = wave >> 2;
    int wn = wave & 3;

    int bid = blockIdx.x;
    int swz = (bid & 7) * 32 + (bid >> 3);
    int m0 = (swz >> 2) * 128;
    int n0 = (swz & 3) * 256;

    int srow = lane >> 2;
    int sk = ((lane & 3) * 8) ^ ((lane & 32) >> 1);
    const unsigned short* pA0 = A  + (size_t)(m0 + wave * 16 + srow) * K + sk;
    const unsigned short* pB0 = Bt + (size_t)(n0 + wave * 16 + srow) * K + sk;
    const unsigned short* pB1 = pB0 + (size_t)128 * K;

    unsigned short* dA  = &lds[0][wave * 512];
    unsigned short* dB0 = &lds[0][4096 + wave * 512];
    unsigned short* dB1 = &lds[0][8192 + wave * 512];

    int off_base = (lane & 15) * 64 + (((lane >> 4) * 16) ^ ((lane & 8) * 4));
    const char* ldsA_rd = (const char*)(&lds[0][0]) + wm * 4096 + off_base;
    const char* ldsB_rd = (const char*)(&lds[0][0]) + 8192 + wn * 4096 + off_base;

    f32x4 acc[4][4] = {};

    STAGE2(0); STAGE2(1); STAGE2(2);
    GATE(6);

    #pragma unroll 1
    for (int j = 0; j < 29; ++j) { G2_TILE(j, true, GATE(6)); }
    G2_TILE(29, false, GATE(3));
    G2_TILE(30, false, GATE(0));
    G2_TILE(31, false, (void)0);

    int col = lane & 15;
    int quad = lane >> 4;
    float bs[4];
    #pragma unroll
    for (int jf = 0; jf < 4; ++jf) bs[jf] = bias[n0 + wn * 64 + jf * 16 + col];
    #pragma unroll
    for (int i = 0; i < 4; ++i) {
        #pragma unroll
        for (int r = 0; r < 4; ++r) {
            int m = m0 + wm * 64 + i * 16 + quad * 4 + r;
            const float* rrow = resid + (size_t)m * D_MODEL + n0 + wn * 64 + col;
            float* orow = out_f + (size_t)m * D_MODEL + n0 + wn * 64 + col;
            #pragma unroll
            for (int jf = 0; jf < 4; ++jf) {
                float y = acc[i][jf][r] + bs[jf] + rrow[jf * 16];
                y = fminf(10.0f, fmaxf(-10.0f, y));
                orow[jf * 16] = y;
            }
        }
    }
}

// ============================================================================
// Fused SSM scan (R4 v1): scan1 + combine + scan2 in one kernel.
// ============================================================================
__global__ __launch_bounds__(512) void scan_fused_kernel(const unsigned short* __restrict__ u,
                                                         const unsigned short* __restrict__ zs,
                                                         const float* __restrict__ A_log,
                                                         const float* __restrict__ Bp,
                                                         const float* __restrict__ Cp,
                                                         const float* __restrict__ log_dt,
                                                         unsigned short* __restrict__ yz) {
    __shared__ float S[N_CHUNK][D_STATE][17];   // 34,816 B; pad 17 vs bank aliasing

    int bid = blockIdx.x;
    int l  = (bid & 7) * 32 + (bid >> 3);   // bijective XCD-chunk swizzle
    int b  = l >> 6;                         // 0..3
    int dg = l & 63;                         // 0..63
    int t  = threadIdx.x;
    int c  = t >> 4;                         // chunk 0..31
    int dl = t & 15;
    int d  = dg * 16 + dl;

    // params
    float dt = fminf(1.0f, fmaxf(1e-4f, __expf(log_dt[d])));
    float ab[D_STATE];
    #pragma unroll
    for (int n = 0; n < D_STATE; n++) {
        float a = __expf(-__expf(A_log[d * D_STATE + n]) * dt);
        ab[n] = fminf(1.0f - 1e-8f, fmaxf(1e-8f, a));
    }

    // ---- pass 1: local chunk scan, cache u in registers ----
    size_t row0 = (size_t)(b * L_SEQ + c * C_LEN);
    const unsigned short* up = u + row0 * D_MODEL + d;

    unsigned int uc[32];          // 64 bf16 packed as 32 x u32
    float P[D_STATE];
    #pragma unroll
    for (int n = 0; n < D_STATE; n++) P[n] = 0.0f;
    #pragma unroll
    for (int tt = 0; tt < 32; tt++) {
        unsigned int lo = up[(size_t)(2 * tt) * D_MODEL];
        unsigned int hi = up[(size_t)(2 * tt + 1) * D_MODEL];
        uc[tt] = lo | (hi << 16);
        float u0 = __uint_as_float(lo << 16);
        float u1 = __uint_as_float(hi << 16);
        #pragma unroll
        for (int n = 0; n < D_STATE; n++) P[n] = fmaf(ab[n], P[n], u0);
        #pragma unroll
        for (int n = 0; n < D_STATE; n++) P[n] = fmaf(ab[n], P[n], u1);
    }

    // publish chunk-final states
    #pragma unroll
    for (int n = 0; n < D_STATE; n++) S[c][n][dl] = P[n];

    // aP = a^64 (uniform across chunks -> constant-coefficient prefix valid)
    float m[D_STATE];
    #pragma unroll
    for (int n = 0; n < D_STATE; n++) {
        float a2 = ab[n];
        #pragma unroll
        for (int q = 0; q < 6; q++) a2 = a2 * a2;
        m[n] = a2;
    }
    __syncthreads();

    // ---- Hillis-Steele inclusive prefix over c: P[c] += m * P[c-k] ----
    #pragma unroll
    for (int k = 1; k < N_CHUNK; k <<= 1) {
        float tmp[D_STATE];
        #pragma unroll
        for (int n = 0; n < D_STATE; n++) tmp[n] = (c >= k) ? S[c - k][n][dl] : 0.0f;
        __syncthreads();
        #pragma unroll
        for (int n = 0; n < D_STATE; n++) {
            P[n] = fmaf(m[n], tmp[n], P[n]);
            S[c][n][dl] = P[n];
        }
        #pragma unroll
        for (int n = 0; n < D_STATE; n++) m[n] = m[n] * m[n];
        __syncthreads();
    }

    // ---- pass 2: rescan with exclusive prefix init, fuse z-gate ----
    float s2[D_STATE];
    #pragma unroll
    for (int n = 0; n < D_STATE; n++) s2[n] = (c == 0) ? 0.0f : S[c - 1][n][dl];

    float cb[D_STATE];
    #pragma unroll
    for (int n = 0; n < D_STATE; n++)
        cb[n] = Cp[d * D_STATE + n] * Bp[d * D_STATE + n] * dt;

    const unsigned short* zp = zs + row0 * D_MODEL + d;
    unsigned short* yp = yz + row0 * D_MODEL + d;

    #pragma unroll
    for (int tt = 0; tt < 32; tt++) {
        unsigned int w = uc[tt];
        float u0 = __uint_as_float(w << 16);
        float u1 = __uint_as_float(w & 0xFFFF0000u);
        float y0 = 0.0f, y1 = 0.0f;
        #pragma unroll
        for (int n = 0; n < D_STATE; n++) s2[n] = fmaf(ab[n], s2[n], u0);
        #pragma unroll
        for (int n = 0; n < D_STATE; n++) y0 = fmaf(cb[n], s2[n], y0);
        #pragma unroll
        for (int n = 0; n < D_STATE; n++) s2[n] = fmaf(ab[n], s2[n], u1);
        #pragma unroll
        for (int n = 0; n < D_STATE; n++) y1 = fmaf(cb[n], s2[n], y1);
        float z0 = bf2f(zp[(size_t)(2 * tt) * D_MODEL]);
        float z1 = bf2f(zp[(size_t)(2 * tt + 1) * D_MODEL]);
        yp[(size_t)(2 * tt) * D_MODEL]     = f2bf(y0 * z0);
        yp[(size_t)(2 * tt + 1) * D_MODEL] = f2bf(y1 * z1);
    }
}

extern "C" void kernel_launch(void* const* d_in, const int* in_sizes, int n_in,
                              void* d_out, int out_size, void* d_ws, size_t ws_size,
                              hipStream_t stream) {
    const float* x       = (const float*)d_in[0];
    const float* A_log   = (const float*)d_in[1];
    const float* B_param = (const float*)d_in[2];
    const float* C_param = (const float*)d_in[3];
    const float* log_dt  = (const float*)d_in[4];
    const float* in_w    = (const float*)d_in[5];
    const float* in_b    = (const float*)d_in[6];
    const float* out_w   = (const float*)d_in[7];
    const float* out_b   = (const float*)d_in[8];
    const float* ln_g    = (const float*)d_in[9];
    const float* ln_b    = (const float*)d_in[10];
    float* out = (float*)d_out;

    char* ws = (char*)d_ws;
    size_t off = 0;
    unsigned short* xn = (unsigned short*)(ws + off); off += (size_t)M_ROWS * D_MODEL * 2;        // 16 MB
    unsigned short* w1 = (unsigned short*)(ws + off); off += (size_t)2 * D_MODEL * D_MODEL * 2;   // 4 MB
    unsigned short* u  = (unsigned short*)(ws + off); off += (size_t)M_ROWS * D_MODEL * 2;        // 16 MB
    unsigned short* zs = (unsigned short*)(ws + off); off += (size_t)M_ROWS * D_MODEL * 2;        // 16 MB
    unsigned short* yz = (unsigned short*)(ws + off); off += (size_t)M_ROWS * D_MODEL * 2;        // 16 MB
    unsigned short* w2 = (unsigned short*)(ws + off); off += (size_t)D_MODEL * D_MODEL * 2;       // 2 MB

    // fused LN + weight conversion
    prep_kernel<<<M_ROWS + 2048 + 1024, 256, 0, stream>>>(x, ln_g, ln_b, xn, in_w, w1, out_w, w2);

    // GEMM1: (8192x1024) @ (2048x1024)^T -> u bf16 / silu(z) bf16
    gemm1_kernel<<<256, 512, 0, stream>>>(xn, w1, in_b, u, zs);

    // fused chunked SSM scan
    scan_fused_kernel<<<256, 512, 0, stream>>>(u, zs, A_log, B_param, C_param, log_dt, yz);

    // GEMM2: (8192x1024) @ (1024x1024)^T + resid, clip
    gemm2_kernel<<<256, 512, 0, stream>>>(yz, w2, out_b, out, x);
}